// Round 4
// baseline (2387.022 us; speedup 1.0000x reference)
//
#include <hip/hip_runtime.h>

// MoE fused: B=4,S=2048,D=1024,E=8,H=4096,TOPK=2, fp32 in/out.
// zero -> gating(fp64 acc, top2, softmax) -> prefix -> convert x -> transpose+convert w1,w2
// -> per-H-chunk: gemm1 (x@w1+b1, relu) -> gemm2 (h@w2+b2, *wgt, atomicAdd out)
// GEMMs: split-bf16 (hi/lo), P passes chosen by ws_size tier (3=full split, 2=acts split, 1=plain bf16).

typedef unsigned short u16;
typedef unsigned int u32;
typedef float f32x4 __attribute__((ext_vector_type(4)));
typedef short s16x8 __attribute__((ext_vector_type(8)));   // 8 bf16 as raw u16 (guide-verified MFMA frag type)
typedef u16 u16x4 __attribute__((ext_vector_type(4)));

#define T_TOK 8192
#define DD 1024
#define EE 8
#define HH 4096

__device__ __forceinline__ u16 f2bf(float f) {
    u32 u = __builtin_bit_cast(u32, f);
    u32 r = u + 0x7FFFu + ((u >> 16) & 1u);   // RNE
    return (u16)(r >> 16);
}
__device__ __forceinline__ float bf2f(u16 h) {
    return __builtin_bit_cast(float, (u32)h << 16);
}
__device__ __forceinline__ void gload16(const u16* g, u16* l) {
    __builtin_amdgcn_global_load_lds((const __attribute__((address_space(1))) void*)g,
                                     (__attribute__((address_space(3))) void*)l, 16, 0, 0);
}

// ---------------- zero out region + counts ----------------
__global__ void k_zero(float* __restrict__ out, int* __restrict__ counts) {
    size_t i = (size_t)blockIdx.x * 256 + threadIdx.x;   // 8192 blocks -> 2M float4 = T*D floats
    f32x4 z = {0.f, 0.f, 0.f, 0.f};
    ((f32x4*)out)[i] = z;
    if (i < EE) counts[i] = 0;
}

// ---------------- gating: fp64-accum logits, top2, softmax over the pair ----------------
__global__ void k_gating(const float* __restrict__ x, const float* __restrict__ gw,
                         float* __restrict__ sel_out, int* __restrict__ counts,
                         int* __restrict__ tok, float* __restrict__ wlist) {
    int t = blockIdx.x * 4 + (threadIdx.x >> 6);
    int l = threadIdx.x & 63;
    const float* xr = x + (size_t)t * DD;
    double acc[EE];
#pragma unroll
    for (int e = 0; e < EE; e++) acc[e] = 0.0;
    for (int d = l; d < DD; d += 64) {
        double xv = (double)xr[d];
        const float* g = gw + (size_t)d * EE;
#pragma unroll
        for (int e = 0; e < EE; e++) acc[e] = fma(xv, (double)g[e], acc[e]);
    }
#pragma unroll
    for (int off = 32; off > 0; off >>= 1) {
#pragma unroll
        for (int e = 0; e < EE; e++) acc[e] += __shfl_down(acc[e], off, 64);
    }
    if (l == 0) {
        float af[EE];
#pragma unroll
        for (int e = 0; e < EE; e++) af[e] = (float)acc[e];
        int i0 = 0; float v0 = af[0];
#pragma unroll
        for (int e = 1; e < EE; e++) if (af[e] > v0) { v0 = af[e]; i0 = e; }
        int i1 = -1; float v1 = -3.4e38f;
#pragma unroll
        for (int e = 0; e < EE; e++) if (e != i0 && af[e] > v1) { v1 = af[e]; i1 = e; }
        float ex = expf(v1 - v0);
        float den = 1.f + ex;
        float w0 = 1.f / den, w1 = ex / den;   // == softmax([v0,v1]) with max subtraction
        sel_out[(size_t)t * 2]     = (float)i0;
        sel_out[(size_t)t * 2 + 1] = (float)i1;
        int s0 = atomicAdd(&counts[i0], 1);
        tok[i0 * T_TOK + s0] = t;  wlist[i0 * T_TOK + s0] = w0;
        int s1 = atomicAdd(&counts[i1], 1);
        tok[i1 * T_TOK + s1] = t;  wlist[i1 * T_TOK + s1] = w1;
    }
}

__global__ void k_prefix(const int* __restrict__ counts, int* __restrict__ offsets) {
    if (threadIdx.x == 0) {
        int s = 0;
        for (int e = 0; e < EE; e++) { offsets[e] = s; s += counts[e]; }
        offsets[EE] = s;
    }
}

// ---------------- convert x -> bf16 hi (+lo) ----------------
template <bool LO>
__global__ void k_convx(const float* __restrict__ x, u16* __restrict__ xh, u16* __restrict__ xl) {
    size_t i = (size_t)blockIdx.x * 256 + threadIdx.x;   // 8192 blocks: T*D/4
    f32x4 v = ((const f32x4*)x)[i];
    u16x4 h, lo;
#pragma unroll
    for (int j = 0; j < 4; j++) {
        u16 hb = f2bf(v[j]);
        h[j] = hb;
        if (LO) lo[j] = f2bf(v[j] - bf2f(hb));
    }
    ((u16x4*)xh)[i] = h;
    if (LO) ((u16x4*)xl)[i] = lo;
}

// ---------------- transpose+convert: [E][R][C] f32 -> [E][C][R] bf16 hi (+lo) ----------------
template <bool LO>
__global__ void k_transconv(const float* __restrict__ src, u16* __restrict__ dh,
                            u16* __restrict__ dl, int R, int C) {
    __shared__ float tile[32][33];
    int e = blockIdx.z;
    int r0 = blockIdx.x * 32, c0 = blockIdx.y * 32;
    int tx = threadIdx.x & 31, ty = threadIdx.x >> 5;
    const float* s = src + (size_t)e * R * C;
#pragma unroll
    for (int j = 0; j < 4; j++)
        tile[ty + j * 8][tx] = s[(size_t)(r0 + ty + j * 8) * C + (c0 + tx)];
    __syncthreads();
    u16* ph = dh + (size_t)e * R * C;
    u16* pl = dl + (size_t)e * R * C;
#pragma unroll
    for (int j = 0; j < 4; j++) {
        float v = tile[tx][ty + j * 8];
        u16 hb = f2bf(v);
        size_t o = (size_t)(c0 + ty + j * 8) * R + (r0 + tx);
        ph[o] = hb;
        if (LO) pl[o] = f2bf(v - bf2f(hb));
    }
}

// ---------------- GEMM1: h[slot][0..HC) = relu(x[tok] @ w1t[:, ncol0..ncol0+HC)^T + b1) ----------------
// P=3: Ah*Bh + Al*Bh + Ah*Bl ; P=2: Ah*Bh + Al*Bh ; P=1: Ah*Bh
template <int P>
__global__ __launch_bounds__(256, 2) void k_gemm1(
    const u16* __restrict__ xh, const u16* __restrict__ xl,
    const u16* __restrict__ wth, const u16* __restrict__ wtl,
    const float* __restrict__ b1,
    const int* __restrict__ counts, const int* __restrict__ offsets,
    const int* __restrict__ tok,
    u16* __restrict__ hh, u16* __restrict__ hl,
    int HC, int ncol0) {
    int e = blockIdx.x >> 6, mt = blockIdx.x & 63, nt = blockIdx.y;
    int count = counts[e];
    if (mt * 128 >= count) return;
    int hbase = offsets[e];

    __shared__ u16 Ash[4096], Bsh[4096];
    __shared__ u16 Asl[(P >= 2) ? 4096 : 64];
    __shared__ u16 Bsl[(P == 3) ? 4096 : 64];

    int tid = threadIdx.x;
    int rA = tid >> 2, kch = tid & 3;
    int slot0 = mt * 128 + rA, slot1 = slot0 + 64;
    int rg0 = (slot0 < count) ? tok[e * T_TOK + slot0] : 0;
    int rg1 = (slot1 < count) ? tok[e * T_TOK + slot1] : 0;
    const u16* a0h = xh + (size_t)rg0 * DD + kch * 8;
    const u16* a1h = xh + (size_t)rg1 * DD + kch * 8;
    const u16* a0l = xl + (size_t)rg0 * DD + kch * 8;
    const u16* a1l = xl + (size_t)rg1 * DD + kch * 8;
    size_t bb0 = ((size_t)e * HH + ncol0 + nt * 128 + rA) * DD + kch * 8;
    size_t bb1 = bb0 + (size_t)64 * DD;
    const u16* pb0h = wth + bb0; const u16* pb1h = wth + bb1;
    const u16* pb0l = wtl + bb0; const u16* pb1l = wtl + bb1;

    u16* dA0 = Ash + tid * 8;  u16* dA1 = Ash + (tid + 256) * 8;
    u16* dB0 = Bsh + tid * 8;  u16* dB1 = Bsh + (tid + 256) * 8;
    u16* dA0l = Asl + tid * 8; u16* dA1l = Asl + (tid + 256) * 8;
    u16* dB0l = Bsl + tid * 8; u16* dB1l = Bsl + (tid + 256) * 8;

    int l = tid & 63, w = tid >> 6;
    int wr = w >> 1, wc = w & 1;
    int lm = l & 15, lk = l >> 4;

    f32x4 acc[4][4];
    f32x4 zero = {0.f, 0.f, 0.f, 0.f};
#pragma unroll
    for (int m = 0; m < 4; m++)
#pragma unroll
        for (int n = 0; n < 4; n++) acc[m][n] = zero;

    int aoff[4], boff[4];
#pragma unroll
    for (int m = 0; m < 4; m++) aoff[m] = (wr * 64 + m * 16 + lm) * 32 + lk * 8;
#pragma unroll
    for (int n = 0; n < 4; n++) boff[n] = (wc * 64 + n * 16 + lm) * 32 + lk * 8;

    for (int k0 = 0; k0 < DD; k0 += 32) {
        __syncthreads();
        gload16(a0h + k0, dA0);
        gload16(a1h + k0, dA1);
        gload16(pb0h + k0, dB0);
        gload16(pb1h + k0, dB1);
        if (P >= 2) { gload16(a0l + k0, dA0l); gload16(a1l + k0, dA1l); }
        if (P == 3) { gload16(pb0l + k0, dB0l); gload16(pb1l + k0, dB1l); }
        __syncthreads();
        s16x8 ah[4], al[4], bh[4], bl[4];
#pragma unroll
        for (int m = 0; m < 4; m++) {
            ah[m] = *(const s16x8*)(Ash + aoff[m]);
            if (P >= 2) al[m] = *(const s16x8*)(Asl + aoff[m]);
        }
#pragma unroll
        for (int n = 0; n < 4; n++) {
            bh[n] = *(const s16x8*)(Bsh + boff[n]);
            if (P == 3) bl[n] = *(const s16x8*)(Bsl + boff[n]);
        }
#pragma unroll
        for (int m = 0; m < 4; m++)
#pragma unroll
            for (int n = 0; n < 4; n++) {
                acc[m][n] = __builtin_amdgcn_mfma_f32_16x16x32_bf16(ah[m], bh[n], acc[m][n], 0, 0, 0);
                if (P >= 2) acc[m][n] = __builtin_amdgcn_mfma_f32_16x16x32_bf16(al[m], bh[n], acc[m][n], 0, 0, 0);
                if (P == 3) acc[m][n] = __builtin_amdgcn_mfma_f32_16x16x32_bf16(ah[m], bl[n], acc[m][n], 0, 0, 0);
            }
    }

#pragma unroll
    for (int n = 0; n < 4; n++) {
        int coln = nt * 128 + wc * 64 + n * 16 + lm;         // local col within chunk
        float bias = b1[e * HH + ncol0 + coln];
#pragma unroll
        for (int m = 0; m < 4; m++) {
#pragma unroll
            for (int j = 0; j < 4; j++) {
                int slot = mt * 128 + wr * 64 + m * 16 + lk * 4 + j;
                if (slot < count) {
                    float v = fmaxf(acc[m][n][j] + bias, 0.f);
                    u16 hb = f2bf(v);
                    size_t o = (size_t)(hbase + slot) * HC + coln;
                    hh[o] = hb;
                    if (P >= 2) hl[o] = f2bf(v - bf2f(hb));
                }
            }
        }
    }
}

// ---------------- GEMM2: out[tok] += wgt * (h @ w2t[:, ncol0..)^T + biasf*b2) ----------------
template <int P>
__global__ __launch_bounds__(256, 2) void k_gemm2(
    const u16* __restrict__ hh, const u16* __restrict__ hl,
    const u16* __restrict__ wth, const u16* __restrict__ wtl,
    const float* __restrict__ b2,
    const int* __restrict__ counts, const int* __restrict__ offsets,
    const int* __restrict__ tok, const float* __restrict__ wlist,
    float* __restrict__ out, int HC, int ncol0, float biasf) {
    int e = blockIdx.x >> 6, mt = blockIdx.x & 63, nt = blockIdx.y;
    int count = counts[e];
    if (mt * 128 >= count) return;
    int hbase = offsets[e];

    __shared__ u16 Ash[4096], Bsh[4096];
    __shared__ u16 Asl[(P >= 2) ? 4096 : 64];
    __shared__ u16 Bsl[(P == 3) ? 4096 : 64];

    int tid = threadIdx.x;
    int rA = tid >> 2, kch = tid & 3;
    int slot0 = mt * 128 + rA, slot1 = slot0 + 64;
    int r0 = hbase + min(slot0, count - 1);
    int r1 = hbase + min(slot1, count - 1);
    const u16* a0h = hh + (size_t)r0 * HC + kch * 8;
    const u16* a1h = hh + (size_t)r1 * HC + kch * 8;
    const u16* a0l = hl + (size_t)r0 * HC + kch * 8;
    const u16* a1l = hl + (size_t)r1 * HC + kch * 8;
    size_t bb0 = ((size_t)e * DD + nt * 128 + rA) * HH + ncol0 + kch * 8;
    size_t bb1 = bb0 + (size_t)64 * HH;
    const u16* pb0h = wth + bb0; const u16* pb1h = wth + bb1;
    const u16* pb0l = wtl + bb0; const u16* pb1l = wtl + bb1;

    u16* dA0 = Ash + tid * 8;  u16* dA1 = Ash + (tid + 256) * 8;
    u16* dB0 = Bsh + tid * 8;  u16* dB1 = Bsh + (tid + 256) * 8;
    u16* dA0l = Asl + tid * 8; u16* dA1l = Asl + (tid + 256) * 8;
    u16* dB0l = Bsl + tid * 8; u16* dB1l = Bsl + (tid + 256) * 8;

    int l = tid & 63, w = tid >> 6;
    int wr = w >> 1, wc = w & 1;
    int lm = l & 15, lk = l >> 4;

    f32x4 acc[4][4];
    f32x4 zero = {0.f, 0.f, 0.f, 0.f};
#pragma unroll
    for (int m = 0; m < 4; m++)
#pragma unroll
        for (int n = 0; n < 4; n++) acc[m][n] = zero;

    int aoff[4], boff[4];
#pragma unroll
    for (int m = 0; m < 4; m++) aoff[m] = (wr * 64 + m * 16 + lm) * 32 + lk * 8;
#pragma unroll
    for (int n = 0; n < 4; n++) boff[n] = (wc * 64 + n * 16 + lm) * 32 + lk * 8;

    for (int k0 = 0; k0 < HC; k0 += 32) {
        __syncthreads();
        gload16(a0h + k0, dA0);
        gload16(a1h + k0, dA1);
        gload16(pb0h + k0, dB0);
        gload16(pb1h + k0, dB1);
        if (P >= 2) { gload16(a0l + k0, dA0l); gload16(a1l + k0, dA1l); }
        if (P == 3) { gload16(pb0l + k0, dB0l); gload16(pb1l + k0, dB1l); }
        __syncthreads();
        s16x8 ah[4], al[4], bh[4], bl[4];
#pragma unroll
        for (int m = 0; m < 4; m++) {
            ah[m] = *(const s16x8*)(Ash + aoff[m]);
            if (P >= 2) al[m] = *(const s16x8*)(Asl + aoff[m]);
        }
#pragma unroll
        for (int n = 0; n < 4; n++) {
            bh[n] = *(const s16x8*)(Bsh + boff[n]);
            if (P == 3) bl[n] = *(const s16x8*)(Bsl + boff[n]);
        }
#pragma unroll
        for (int m = 0; m < 4; m++)
#pragma unroll
            for (int n = 0; n < 4; n++) {
                acc[m][n] = __builtin_amdgcn_mfma_f32_16x16x32_bf16(ah[m], bh[n], acc[m][n], 0, 0, 0);
                if (P >= 2) acc[m][n] = __builtin_amdgcn_mfma_f32_16x16x32_bf16(al[m], bh[n], acc[m][n], 0, 0, 0);
                if (P == 3) acc[m][n] = __builtin_amdgcn_mfma_f32_16x16x32_bf16(ah[m], bl[n], acc[m][n], 0, 0, 0);
            }
    }

#pragma unroll
    for (int m = 0; m < 4; m++) {
        int tk[4]; float wt[4];
#pragma unroll
        for (int j = 0; j < 4; j++) {
            int slot = mt * 128 + wr * 64 + m * 16 + lk * 4 + j;
            if (slot < count) { tk[j] = tok[e * T_TOK + slot]; wt[j] = wlist[e * T_TOK + slot]; }
            else { tk[j] = -1; wt[j] = 0.f; }
        }
#pragma unroll
        for (int n = 0; n < 4; n++) {
            int coln = nt * 128 + wc * 64 + n * 16 + lm;
            float bias = biasf * b2[e * DD + coln];
#pragma unroll
            for (int j = 0; j < 4; j++) {
                if (tk[j] >= 0)
                    atomicAdd(out + (size_t)tk[j] * DD + coln, wt[j] * (acc[m][n][j] + bias));
            }
        }
    }
}

extern "C" void kernel_launch(void* const* d_in, const int* in_sizes, int n_in,
                              void* d_out, int out_size, void* d_ws, size_t ws_size,
                              hipStream_t stream) {
    const float* x  = (const float*)d_in[0];
    const float* gw = (const float*)d_in[1];
    const float* w1 = (const float*)d_in[2];
    const float* b1 = (const float*)d_in[3];
    const float* w2 = (const float*)d_in[4];
    const float* b2 = (const float*)d_in[5];
    float* out = (float*)d_out;

    // ---- tier & chunk selection from ws_size (deterministic; graph-capture-safe) ----
    auto need = [](int P, int hc) -> size_t {
        size_t s = 1 << 20;                                          // ctrl + align slop
        s += (size_t)T_TOK * DD * 2 * (P >= 2 ? 2 : 1);              // x hi (+lo)
        s += (size_t)EE * HH * DD * 2 * 2 * (P == 3 ? 2 : 1);        // w1t+w2t hi (+lo)
        s += (size_t)2 * T_TOK * hc * 2 * (P >= 2 ? 2 : 1);          // h chunk hi (+lo)
        return s;
    };
    int P = 3;
    if (need(3, 128) > ws_size) P = 2;
    if (P == 2 && need(2, 128) > ws_size) P = 1;
    int HC = 128;
    const int hcs[6] = {4096, 2048, 1024, 512, 256, 128};
    for (int i = 0; i < 6; i++) if (need(P, hcs[i]) <= ws_size) { HC = hcs[i]; break; }

    // ---- workspace layout ----
    char* ws = (char*)d_ws;
    size_t p = 0;
    auto take = [&](size_t bytes) { size_t o = p; p = (p + bytes + 255) & ~(size_t)255; return o; };
    int*   counts  = (int*)(ws + take(64));
    int*   offsets = (int*)(ws + take(64));
    int*   tok     = (int*)(ws + take((size_t)EE * T_TOK * 4));
    float* wlist   = (float*)(ws + take((size_t)EE * T_TOK * 4));
    u16*   xhp     = (u16*)(ws + take((size_t)T_TOK * DD * 2));
    u16*   xlp     = (P >= 2) ? (u16*)(ws + take((size_t)T_TOK * DD * 2)) : nullptr;
    u16*   w1th    = (u16*)(ws + take((size_t)EE * HH * DD * 2));
    u16*   w2th    = (u16*)(ws + take((size_t)EE * HH * DD * 2));
    u16*   w1tl    = (P == 3) ? (u16*)(ws + take((size_t)EE * HH * DD * 2)) : nullptr;
    u16*   w2tl    = (P == 3) ? (u16*)(ws + take((size_t)EE * HH * DD * 2)) : nullptr;
    u16*   hhp     = (u16*)(ws + take((size_t)2 * T_TOK * HC * 2));
    u16*   hlp     = (P >= 2) ? (u16*)(ws + take((size_t)2 * T_TOK * HC * 2)) : nullptr;

    // ---- pipeline ----
    k_zero<<<8192, 256, 0, stream>>>(out, counts);
    k_gating<<<2048, 256, 0, stream>>>(x, gw, out + (size_t)T_TOK * DD, counts, tok, wlist);
    k_prefix<<<1, 64, 0, stream>>>(counts, offsets);
    if (P >= 2) k_convx<true><<<8192, 256, 0, stream>>>(x, xhp, xlp);
    else        k_convx<false><<<8192, 256, 0, stream>>>(x, xhp, nullptr);
    if (P == 3) {
        k_transconv<true><<<dim3(32, 128, 8), 256, 0, stream>>>(w1, w1th, w1tl, DD, HH);
        k_transconv<true><<<dim3(128, 32, 8), 256, 0, stream>>>(w2, w2th, w2tl, HH, DD);
    } else {
        k_transconv<false><<<dim3(32, 128, 8), 256, 0, stream>>>(w1, w1th, nullptr, DD, HH);
        k_transconv<false><<<dim3(128, 32, 8), 256, 0, stream>>>(w2, w2th, nullptr, HH, DD);
    }
    int nchunk = HH / HC;
    for (int c = 0; c < nchunk; c++) {
        int ncol0 = c * HC;
        float biasf = (c == 0) ? 1.f : 0.f;
        dim3 g1(EE * 64, HC / 128), g2(EE * 64, DD / 128);
        if (P == 3) {
            k_gemm1<3><<<g1, 256, 0, stream>>>(xhp, xlp, w1th, w1tl, b1, counts, offsets, tok, hhp, hlp, HC, ncol0);
            k_gemm2<3><<<g2, 256, 0, stream>>>(hhp, hlp, w2th, w2tl, b2, counts, offsets, tok, wlist, out, HC, ncol0, biasf);
        } else if (P == 2) {
            k_gemm1<2><<<g1, 256, 0, stream>>>(xhp, xlp, w1th, nullptr, b1, counts, offsets, tok, hhp, hlp, HC, ncol0);
            k_gemm2<2><<<g2, 256, 0, stream>>>(hhp, hlp, w2th, nullptr, b2, counts, offsets, tok, wlist, out, HC, ncol0, biasf);
        } else {
            k_gemm1<1><<<g1, 256, 0, stream>>>(xhp, nullptr, w1th, nullptr, b1, counts, offsets, tok, hhp, nullptr, HC, ncol0);
            k_gemm2<1><<<g2, 256, 0, stream>>>(hhp, nullptr, w2th, nullptr, b2, counts, offsets, tok, wlist, out, HC, ncol0, biasf);
        }
    }
}

// Round 6
// 1979.268 us; speedup vs baseline: 1.2060x; 1.2060x over previous
//
#include <hip/hip_runtime.h>

// MoE fused: B=4,S=2048,D=1024,E=8,H=4096,TOPK=2, fp32 in/out.
// zero -> gating(fp64 acc, top2, softmax) -> prefix -> convert x -> transpose+convert w1,w2
// -> per-H-chunk: gemm1 (x@w1+b1, relu) -> gemm2 (h@w2+b2, *wgt, atomicAdd out)
// GEMMs: split-bf16 (hi/lo), P passes by ws_size tier (3=full split, 2=acts split, 1=plain bf16).
// R5/R6: 2-phase double-buffered prefetch (stage k+1 before compute k; single __syncthreads per
//     K-step) + 1-D grid with nt-fastest decomposition + bijective XCD chunking (A-tile reuse).

typedef unsigned short u16;
typedef unsigned int u32;
typedef float f32x4 __attribute__((ext_vector_type(4)));
typedef short s16x8 __attribute__((ext_vector_type(8)));
typedef u16 u16x4 __attribute__((ext_vector_type(4)));

#define T_TOK 8192
#define DD 1024
#define EE 8
#define HH 4096

__device__ __forceinline__ u16 f2bf(float f) {
    u32 u = __builtin_bit_cast(u32, f);
    u32 r = u + 0x7FFFu + ((u >> 16) & 1u);   // RNE
    return (u16)(r >> 16);
}
__device__ __forceinline__ float bf2f(u16 h) {
    return __builtin_bit_cast(float, (u32)h << 16);
}
__device__ __forceinline__ void gload16(const u16* g, u16* l) {
    __builtin_amdgcn_global_load_lds((const __attribute__((address_space(1))) void*)g,
                                     (__attribute__((address_space(3))) void*)l, 16, 0, 0);
}

// ---------------- zero out region + counts ----------------
__global__ void k_zero(float* __restrict__ out, int* __restrict__ counts) {
    size_t i = (size_t)blockIdx.x * 256 + threadIdx.x;   // T*D floats as float4
    f32x4 z = {0.f, 0.f, 0.f, 0.f};
    ((f32x4*)out)[i] = z;
    if (i < EE) counts[i] = 0;
}

// ---------------- gating: fp64-accum logits, top2, softmax over the pair ----------------
__global__ void k_gating(const float* __restrict__ x, const float* __restrict__ gw,
                         float* __restrict__ sel_out, int* __restrict__ counts,
                         int* __restrict__ tok, float* __restrict__ wlist) {
    int t = blockIdx.x * 4 + (threadIdx.x >> 6);
    int l = threadIdx.x & 63;
    const float* xr = x + (size_t)t * DD;
    double acc[EE];
#pragma unroll
    for (int e = 0; e < EE; e++) acc[e] = 0.0;
    for (int d = l; d < DD; d += 64) {
        double xv = (double)xr[d];
        const float* g = gw + (size_t)d * EE;
#pragma unroll
        for (int e = 0; e < EE; e++) acc[e] = fma(xv, (double)g[e], acc[e]);
    }
#pragma unroll
    for (int off = 32; off > 0; off >>= 1) {
#pragma unroll
        for (int e = 0; e < EE; e++) acc[e] += __shfl_down(acc[e], off, 64);
    }
    if (l == 0) {
        float af[EE];
#pragma unroll
        for (int e = 0; e < EE; e++) af[e] = (float)acc[e];
        int i0 = 0; float v0 = af[0];
#pragma unroll
        for (int e = 1; e < EE; e++) if (af[e] > v0) { v0 = af[e]; i0 = e; }
        int i1 = -1; float v1 = -3.4e38f;
#pragma unroll
        for (int e = 0; e < EE; e++) if (e != i0 && af[e] > v1) { v1 = af[e]; i1 = e; }
        float ex = expf(v1 - v0);
        float den = 1.f + ex;
        float w0 = 1.f / den, w1 = ex / den;
        sel_out[(size_t)t * 2]     = (float)i0;
        sel_out[(size_t)t * 2 + 1] = (float)i1;
        int s0 = atomicAdd(&counts[i0], 1);
        tok[i0 * T_TOK + s0] = t;  wlist[i0 * T_TOK + s0] = w0;
        int s1 = atomicAdd(&counts[i1], 1);
        tok[i1 * T_TOK + s1] = t;  wlist[i1 * T_TOK + s1] = w1;
    }
}

__global__ void k_prefix(const int* __restrict__ counts, int* __restrict__ offsets) {
    if (threadIdx.x == 0) {
        int s = 0;
        for (int e = 0; e < EE; e++) { offsets[e] = s; s += counts[e]; }
        offsets[EE] = s;
    }
}

// ---------------- convert x -> bf16 hi (+lo) ----------------
template <bool LO>
__global__ void k_convx(const float* __restrict__ x, u16* __restrict__ xh, u16* __restrict__ xl) {
    size_t i = (size_t)blockIdx.x * 256 + threadIdx.x;
    f32x4 v = ((const f32x4*)x)[i];
    u16x4 h, lo;
#pragma unroll
    for (int j = 0; j < 4; j++) {
        u16 hb = f2bf(v[j]);
        h[j] = hb;
        if (LO) lo[j] = f2bf(v[j] - bf2f(hb));
    }
    ((u16x4*)xh)[i] = h;
    if (LO) ((u16x4*)xl)[i] = lo;
}

// ---------------- transpose+convert: [E][R][C] f32 -> [E][C][R] bf16 hi (+lo) ----------------
template <bool LO>
__global__ void k_transconv(const float* __restrict__ src, u16* __restrict__ dh,
                            u16* __restrict__ dl, int R, int C) {
    __shared__ float tile[32][33];
    int e = blockIdx.z;
    int r0 = blockIdx.x * 32, c0 = blockIdx.y * 32;
    int tx = threadIdx.x & 31, ty = threadIdx.x >> 5;
    const float* s = src + (size_t)e * R * C;
#pragma unroll
    for (int j = 0; j < 4; j++)
        tile[ty + j * 8][tx] = s[(size_t)(r0 + ty + j * 8) * C + (c0 + tx)];
    __syncthreads();
    u16* ph = dh + (size_t)e * R * C;
    u16* pl = dl + (size_t)e * R * C;
#pragma unroll
    for (int j = 0; j < 4; j++) {
        float v = tile[tx][ty + j * 8];
        u16 hb = f2bf(v);
        size_t o = (size_t)(c0 + ty + j * 8) * R + (r0 + tx);
        ph[o] = hb;
        if (LO) pl[o] = f2bf(v - bf2f(hb));
    }
}

// ---------------- GEMM1: h[slot][0..HC) = relu(x[tok] @ w1t[:, ncol0+...]^T + b1) ----------------
// 2-phase dbuf prefetch. Grid: 1-D, XCD-chunked; decomposition nt-fastest (A-tile reuse).
template <int P>
__global__ __launch_bounds__(256, 2) void k_gemm1(
    const u16* __restrict__ xh, const u16* __restrict__ xl,
    const u16* __restrict__ wth, const u16* __restrict__ wtl,
    const float* __restrict__ b1,
    const int* __restrict__ counts, const int* __restrict__ offsets,
    const int* __restrict__ tok,
    u16* __restrict__ hh, u16* __restrict__ hl,
    int HC, int ncol0, int NTB) {
    // bijective XCD chunking (nwg % 8 == 0 by construction: nwg = 8*64*NTB)
    int nwg = gridDim.x;
    int cpx = nwg >> 3;
    int bid = blockIdx.x;
    int swz = (bid & 7) * cpx + (bid >> 3);
    int nt = swz % NTB; int rem = swz / NTB;
    int mt = rem & 63;  int e = rem >> 6;
    int count = counts[e];
    if (mt * 128 >= count) return;
    int hbase = offsets[e];

    __shared__ u16 Ash[2][4096], Bsh[2][4096];
    __shared__ u16 Asl[(P >= 2) ? 2 : 1][(P >= 2) ? 4096 : 64];
    __shared__ u16 Bsl[(P == 3) ? 2 : 1][(P == 3) ? 4096 : 64];

    int tid = threadIdx.x;
    int rA = tid >> 2, kch = tid & 3;
    int slot0 = mt * 128 + rA, slot1 = slot0 + 64;
    int rg0 = (slot0 < count) ? tok[e * T_TOK + slot0] : 0;
    int rg1 = (slot1 < count) ? tok[e * T_TOK + slot1] : 0;
    const u16* a0h = xh + (size_t)rg0 * DD + kch * 8;
    const u16* a1h = xh + (size_t)rg1 * DD + kch * 8;
    const u16* a0l = xl + (size_t)rg0 * DD + kch * 8;
    const u16* a1l = xl + (size_t)rg1 * DD + kch * 8;
    size_t bb0 = ((size_t)e * HH + ncol0 + nt * 128 + rA) * DD + kch * 8;
    size_t bb1 = bb0 + (size_t)64 * DD;
    const u16* pb0h = wth + bb0; const u16* pb1h = wth + bb1;
    const u16* pb0l = wtl + bb0; const u16* pb1l = wtl + bb1;

    int l = tid & 63, w = tid >> 6;
    int wr = w >> 1, wc = w & 1;
    int lm = l & 15, lk = l >> 4;

    f32x4 acc[4][4];
    f32x4 zero = {0.f, 0.f, 0.f, 0.f};
#pragma unroll
    for (int m = 0; m < 4; m++)
#pragma unroll
        for (int n = 0; n < 4; n++) acc[m][n] = zero;

    int aoff[4], boff[4];
#pragma unroll
    for (int m = 0; m < 4; m++) aoff[m] = (wr * 64 + m * 16 + lm) * 32 + lk * 8;
#pragma unroll
    for (int n = 0; n < 4; n++) boff[n] = (wc * 64 + n * 16 + lm) * 32 + lk * 8;

    int o0 = tid * 8, o1 = (tid + 256) * 8;
    auto stage = [&](int cb, int k0) {
        gload16(a0h + k0, &Ash[cb][o0]);
        gload16(a1h + k0, &Ash[cb][o1]);
        gload16(pb0h + k0, &Bsh[cb][o0]);
        gload16(pb1h + k0, &Bsh[cb][o1]);
        if (P >= 2) { gload16(a0l + k0, &Asl[cb][o0]); gload16(a1l + k0, &Asl[cb][o1]); }
        if (P == 3) { gload16(pb0l + k0, &Bsl[cb][o0]); gload16(pb1l + k0, &Bsl[cb][o1]); }
    };

    const int nsteps = DD / 32;
    stage(0, 0);
    __syncthreads();            // tile 0 landed (barrier implies vmcnt(0) drain)
    int cur = 0;
    for (int it = 0; it < nsteps; ++it) {
        if (it + 1 < nsteps) stage(cur ^ 1, (it + 1) * 32);   // issue next tile; flies during compute
        s16x8 ah[4], al[4], bh[4], bl[4];
#pragma unroll
        for (int m = 0; m < 4; m++) {
            ah[m] = *(const s16x8*)(&Ash[cur][aoff[m]]);
            if (P >= 2) al[m] = *(const s16x8*)(&Asl[cur][aoff[m]]);
        }
#pragma unroll
        for (int n = 0; n < 4; n++) {
            bh[n] = *(const s16x8*)(&Bsh[cur][boff[n]]);
            if (P == 3) bl[n] = *(const s16x8*)(&Bsl[cur][boff[n]]);
        }
#pragma unroll
        for (int m = 0; m < 4; m++)
#pragma unroll
            for (int n = 0; n < 4; n++) {
                acc[m][n] = __builtin_amdgcn_mfma_f32_16x16x32_bf16(ah[m], bh[n], acc[m][n], 0, 0, 0);
                if (P >= 2) acc[m][n] = __builtin_amdgcn_mfma_f32_16x16x32_bf16(al[m], bh[n], acc[m][n], 0, 0, 0);
                if (P == 3) acc[m][n] = __builtin_amdgcn_mfma_f32_16x16x32_bf16(ah[m], bl[n], acc[m][n], 0, 0, 0);
            }
        if (it + 1 < nsteps) {
            __syncthreads();    // drains next-tile loads (vmcnt 0) + joins waves; race-free
            cur ^= 1;
        }
    }

#pragma unroll
    for (int n = 0; n < 4; n++) {
        int coln = nt * 128 + wc * 64 + n * 16 + lm;
        float bias = b1[e * HH + ncol0 + coln];
#pragma unroll
        for (int m = 0; m < 4; m++) {
#pragma unroll
            for (int j = 0; j < 4; j++) {
                int slot = mt * 128 + wr * 64 + m * 16 + lk * 4 + j;
                if (slot < count) {
                    float v = fmaxf(acc[m][n][j] + bias, 0.f);
                    u16 hb = f2bf(v);
                    size_t o = (size_t)(hbase + slot) * HC + coln;
                    hh[o] = hb;
                    if (P >= 2) hl[o] = f2bf(v - bf2f(hb));
                }
            }
        }
    }
}

// ---------------- GEMM2: out[tok] += wgt * (h @ w2t[:, ncol0..]^T + biasf*b2) ----------------
template <int P>
__global__ __launch_bounds__(256, 2) void k_gemm2(
    const u16* __restrict__ hh, const u16* __restrict__ hl,
    const u16* __restrict__ wth, const u16* __restrict__ wtl,
    const float* __restrict__ b2,
    const int* __restrict__ counts, const int* __restrict__ offsets,
    const int* __restrict__ tok, const float* __restrict__ wlist,
    float* __restrict__ out, int HC, int ncol0, float biasf) {
    const int NTB = DD / 128;   // 8
    int nwg = gridDim.x;
    int cpx = nwg >> 3;
    int bid = blockIdx.x;
    int swz = (bid & 7) * cpx + (bid >> 3);
    int nt = swz % NTB; int rem = swz / NTB;
    int mt = rem & 63;  int e = rem >> 6;
    int count = counts[e];
    if (mt * 128 >= count) return;
    int hbase = offsets[e];

    __shared__ u16 Ash[2][4096], Bsh[2][4096];
    __shared__ u16 Asl[(P >= 2) ? 2 : 1][(P >= 2) ? 4096 : 64];
    __shared__ u16 Bsl[(P == 3) ? 2 : 1][(P == 3) ? 4096 : 64];

    int tid = threadIdx.x;
    int rA = tid >> 2, kch = tid & 3;
    int slot0 = mt * 128 + rA, slot1 = slot0 + 64;
    int r0 = hbase + min(slot0, count - 1);
    int r1 = hbase + min(slot1, count - 1);
    const u16* a0h = hh + (size_t)r0 * HC + kch * 8;
    const u16* a1h = hh + (size_t)r1 * HC + kch * 8;
    const u16* a0l = hl + (size_t)r0 * HC + kch * 8;
    const u16* a1l = hl + (size_t)r1 * HC + kch * 8;
    size_t bb0 = ((size_t)e * DD + nt * 128 + rA) * HH + ncol0 + kch * 8;
    size_t bb1 = bb0 + (size_t)64 * HH;
    const u16* pb0h = wth + bb0; const u16* pb1h = wth + bb1;
    const u16* pb0l = wtl + bb0; const u16* pb1l = wtl + bb1;

    int l = tid & 63, w = tid >> 6;
    int wr = w >> 1, wc = w & 1;
    int lm = l & 15, lk = l >> 4;

    f32x4 acc[4][4];
    f32x4 zero = {0.f, 0.f, 0.f, 0.f};
#pragma unroll
    for (int m = 0; m < 4; m++)
#pragma unroll
        for (int n = 0; n < 4; n++) acc[m][n] = zero;

    int aoff[4], boff[4];
#pragma unroll
    for (int m = 0; m < 4; m++) aoff[m] = (wr * 64 + m * 16 + lm) * 32 + lk * 8;
#pragma unroll
    for (int n = 0; n < 4; n++) boff[n] = (wc * 64 + n * 16 + lm) * 32 + lk * 8;

    int o0 = tid * 8, o1 = (tid + 256) * 8;
    auto stage = [&](int cb, int k0) {
        gload16(a0h + k0, &Ash[cb][o0]);
        gload16(a1h + k0, &Ash[cb][o1]);
        gload16(pb0h + k0, &Bsh[cb][o0]);
        gload16(pb1h + k0, &Bsh[cb][o1]);
        if (P >= 2) { gload16(a0l + k0, &Asl[cb][o0]); gload16(a1l + k0, &Asl[cb][o1]); }
        if (P == 3) { gload16(pb0l + k0, &Bsl[cb][o0]); gload16(pb1l + k0, &Bsl[cb][o1]); }
    };

    const int nsteps = HC / 32;
    stage(0, 0);
    __syncthreads();
    int cur = 0;
    for (int it = 0; it < nsteps; ++it) {
        if (it + 1 < nsteps) stage(cur ^ 1, (it + 1) * 32);
        s16x8 ah[4], al[4], bh[4], bl[4];
#pragma unroll
        for (int m = 0; m < 4; m++) {
            ah[m] = *(const s16x8*)(&Ash[cur][aoff[m]]);
            if (P >= 2) al[m] = *(const s16x8*)(&Asl[cur][aoff[m]]);
        }
#pragma unroll
        for (int n = 0; n < 4; n++) {
            bh[n] = *(const s16x8*)(&Bsh[cur][boff[n]]);
            if (P == 3) bl[n] = *(const s16x8*)(&Bsl[cur][boff[n]]);
        }
#pragma unroll
        for (int m = 0; m < 4; m++)
#pragma unroll
            for (int n = 0; n < 4; n++) {
                acc[m][n] = __builtin_amdgcn_mfma_f32_16x16x32_bf16(ah[m], bh[n], acc[m][n], 0, 0, 0);
                if (P >= 2) acc[m][n] = __builtin_amdgcn_mfma_f32_16x16x32_bf16(al[m], bh[n], acc[m][n], 0, 0, 0);
                if (P == 3) acc[m][n] = __builtin_amdgcn_mfma_f32_16x16x32_bf16(ah[m], bl[n], acc[m][n], 0, 0, 0);
            }
        if (it + 1 < nsteps) {
            __syncthreads();
            cur ^= 1;
        }
    }

#pragma unroll
    for (int m = 0; m < 4; m++) {
        int tk[4]; float wt[4];
#pragma unroll
        for (int j = 0; j < 4; j++) {
            int slot = mt * 128 + wr * 64 + m * 16 + lk * 4 + j;
            if (slot < count) { tk[j] = tok[e * T_TOK + slot]; wt[j] = wlist[e * T_TOK + slot]; }
            else { tk[j] = -1; wt[j] = 0.f; }
        }
#pragma unroll
        for (int n = 0; n < 4; n++) {
            int coln = nt * 128 + wc * 64 + n * 16 + lm;
            float bias = biasf * b2[e * DD + coln];
#pragma unroll
            for (int j = 0; j < 4; j++) {
                if (tk[j] >= 0)
                    atomicAdd(out + (size_t)tk[j] * DD + coln, wt[j] * (acc[m][n][j] + bias));
            }
        }
    }
}

extern "C" void kernel_launch(void* const* d_in, const int* in_sizes, int n_in,
                              void* d_out, int out_size, void* d_ws, size_t ws_size,
                              hipStream_t stream) {
    const float* x  = (const float*)d_in[0];
    const float* gw = (const float*)d_in[1];
    const float* w1 = (const float*)d_in[2];
    const float* b1 = (const float*)d_in[3];
    const float* w2 = (const float*)d_in[4];
    const float* b2 = (const float*)d_in[5];
    float* out = (float*)d_out;

    // ---- tier & chunk selection from ws_size (deterministic; graph-capture-safe) ----
    auto need = [](int P, int hc) -> size_t {
        size_t s = 1 << 20;
        s += (size_t)T_TOK * DD * 2 * (P >= 2 ? 2 : 1);
        s += (size_t)EE * HH * DD * 2 * 2 * (P == 3 ? 2 : 1);
        s += (size_t)2 * T_TOK * hc * 2 * (P >= 2 ? 2 : 1);
        return s;
    };
    int P = 3;
    if (need(3, 128) > ws_size) P = 2;
    if (P == 2 && need(2, 128) > ws_size) P = 1;
    int HC = 128;
    const int hcs[6] = {4096, 2048, 1024, 512, 256, 128};
    for (int i = 0; i < 6; i++) if (need(P, hcs[i]) <= ws_size) { HC = hcs[i]; break; }

    // ---- workspace layout ----
    char* ws = (char*)d_ws;
    size_t p = 0;
    auto take = [&](size_t bytes) { size_t o = p; p = (p + bytes + 255) & ~(size_t)255; return o; };
    int*   counts  = (int*)(ws + take(64));
    int*   offsets = (int*)(ws + take(64));
    int*   tok     = (int*)(ws + take((size_t)EE * T_TOK * 4));
    float* wlist   = (float*)(ws + take((size_t)EE * T_TOK * 4));
    u16*   xhp     = (u16*)(ws + take((size_t)T_TOK * DD * 2));
    u16*   xlp     = (P >= 2) ? (u16*)(ws + take((size_t)T_TOK * DD * 2)) : nullptr;
    u16*   w1th    = (u16*)(ws + take((size_t)EE * HH * DD * 2));
    u16*   w2th    = (u16*)(ws + take((size_t)EE * HH * DD * 2));
    u16*   w1tl    = (P == 3) ? (u16*)(ws + take((size_t)EE * HH * DD * 2)) : nullptr;
    u16*   w2tl    = (P == 3) ? (u16*)(ws + take((size_t)EE * HH * DD * 2)) : nullptr;
    u16*   hhp     = (u16*)(ws + take((size_t)2 * T_TOK * HC * 2));
    u16*   hlp     = (P >= 2) ? (u16*)(ws + take((size_t)2 * T_TOK * HC * 2)) : nullptr;

    // ---- pipeline ----
    k_zero<<<8192, 256, 0, stream>>>(out, counts);
    k_gating<<<2048, 256, 0, stream>>>(x, gw, out + (size_t)T_TOK * DD, counts, tok, wlist);
    k_prefix<<<1, 64, 0, stream>>>(counts, offsets);
    if (P >= 2) k_convx<true><<<8192, 256, 0, stream>>>(x, xhp, xlp);
    else        k_convx<false><<<8192, 256, 0, stream>>>(x, xhp, nullptr);
    if (P == 3) {
        k_transconv<true><<<dim3(32, 128, 8), 256, 0, stream>>>(w1, w1th, w1tl, DD, HH);
        k_transconv<true><<<dim3(128, 32, 8), 256, 0, stream>>>(w2, w2th, w2tl, HH, DD);
    } else {
        k_transconv<false><<<dim3(32, 128, 8), 256, 0, stream>>>(w1, w1th, nullptr, DD, HH);
        k_transconv<false><<<dim3(128, 32, 8), 256, 0, stream>>>(w2, w2th, nullptr, HH, DD);
    }
    int nchunk = HH / HC;
    int NTB1 = HC / 128;
    dim3 g1(EE * 64 * NTB1), g2(EE * 64 * (DD / 128));
    for (int c = 0; c < nchunk; c++) {
        int ncol0 = c * HC;
        float biasf = (c == 0) ? 1.f : 0.f;
        if (P == 3) {
            k_gemm1<3><<<g1, 256, 0, stream>>>(xhp, xlp, w1th, w1tl, b1, counts, offsets, tok, hhp, hlp, HC, ncol0, NTB1);
            k_gemm2<3><<<g2, 256, 0, stream>>>(hhp, hlp, w2th, w2tl, b2, counts, offsets, tok, wlist, out, HC, ncol0, biasf);
        } else if (P == 2) {
            k_gemm1<2><<<g1, 256, 0, stream>>>(xhp, xlp, w1th, nullptr, b1, counts, offsets, tok, hhp, hlp, HC, ncol0, NTB1);
            k_gemm2<2><<<g2, 256, 0, stream>>>(hhp, hlp, w2th, nullptr, b2, counts, offsets, tok, wlist, out, HC, ncol0, biasf);
        } else {
            k_gemm1<1><<<g1, 256, 0, stream>>>(xhp, nullptr, w1th, nullptr, b1, counts, offsets, tok, hhp, nullptr, HC, ncol0, NTB1);
            k_gemm2<1><<<g2, 256, 0, stream>>>(hhp, nullptr, w2th, nullptr, b2, counts, offsets, tok, wlist, out, HC, ncol0, biasf);
        }
    }
}

// Round 9
// 1401.240 us; speedup vs baseline: 1.7035x; 1.4125x over previous
//
#include <hip/hip_runtime.h>

// MoE fused: B=4,S=2048,D=1024,E=8,H=4096,TOPK=2, fp32 in/out.
// zero -> gating(fp64 acc, top2, softmax) -> prefix -> convert x -> transpose+convert w1,w2
// -> gemm1 (x@w1+b1, relu) -> gemm2 (h@w2+b2, *wgt, atomicAdd out)   [single chunk at HC=4096]
// GEMMs: split-bf16. R7-R9: default tier P=2 (acts hi/lo, weights single bf16) -> 2/3 MFMA work,
//   6 stage-loads/K-step, LDS 48KB => 3 blocks/CU. 2-phase dbuf prefetch + bijective XCD chunk.

typedef unsigned short u16;
typedef unsigned int u32;
typedef float f32x4 __attribute__((ext_vector_type(4)));
typedef short s16x8 __attribute__((ext_vector_type(8)));
typedef u16 u16x4 __attribute__((ext_vector_type(4)));

#define T_TOK 8192
#define DD 1024
#define EE 8
#define HH 4096

__device__ __forceinline__ u16 f2bf(float f) {
    u32 u = __builtin_bit_cast(u32, f);
    u32 r = u + 0x7FFFu + ((u >> 16) & 1u);   // RNE
    return (u16)(r >> 16);
}
__device__ __forceinline__ float bf2f(u16 h) {
    return __builtin_bit_cast(float, (u32)h << 16);
}
__device__ __forceinline__ void gload16(const u16* g, u16* l) {
    __builtin_amdgcn_global_load_lds((const __attribute__((address_space(1))) void*)g,
                                     (__attribute__((address_space(3))) void*)l, 16, 0, 0);
}

// ---------------- zero out region + counts ----------------
__global__ void k_zero(float* __restrict__ out, int* __restrict__ counts) {
    size_t i = (size_t)blockIdx.x * 256 + threadIdx.x;   // T*D floats as float4
    f32x4 z = {0.f, 0.f, 0.f, 0.f};
    ((f32x4*)out)[i] = z;
    if (i < EE) counts[i] = 0;
}

// ---------------- gating: fp64-accum logits, top2, softmax over the pair ----------------
__global__ void k_gating(const float* __restrict__ x, const float* __restrict__ gw,
                         float* __restrict__ sel_out, int* __restrict__ counts,
                         int* __restrict__ tok, float* __restrict__ wlist) {
    int t = blockIdx.x * 4 + (threadIdx.x >> 6);
    int l = threadIdx.x & 63;
    const float* xr = x + (size_t)t * DD;
    double acc[EE];
#pragma unroll
    for (int e = 0; e < EE; e++) acc[e] = 0.0;
    for (int d = l; d < DD; d += 64) {
        double xv = (double)xr[d];
        const float* g = gw + (size_t)d * EE;
#pragma unroll
        for (int e = 0; e < EE; e++) acc[e] = fma(xv, (double)g[e], acc[e]);
    }
#pragma unroll
    for (int off = 32; off > 0; off >>= 1) {
#pragma unroll
        for (int e = 0; e < EE; e++) acc[e] += __shfl_down(acc[e], off, 64);
    }
    if (l == 0) {
        float af[EE];
#pragma unroll
        for (int e = 0; e < EE; e++) af[e] = (float)acc[e];
        int i0 = 0; float v0 = af[0];
#pragma unroll
        for (int e = 1; e < EE; e++) if (af[e] > v0) { v0 = af[e]; i0 = e; }
        int i1 = -1; float v1 = -3.4e38f;
#pragma unroll
        for (int e = 0; e < EE; e++) if (e != i0 && af[e] > v1) { v1 = af[e]; i1 = e; }
        float ex = expf(v1 - v0);
        float den = 1.f + ex;
        float w0 = 1.f / den, w1 = ex / den;
        sel_out[(size_t)t * 2]     = (float)i0;
        sel_out[(size_t)t * 2 + 1] = (float)i1;
        int s0 = atomicAdd(&counts[i0], 1);
        tok[i0 * T_TOK + s0] = t;  wlist[i0 * T_TOK + s0] = w0;
        int s1 = atomicAdd(&counts[i1], 1);
        tok[i1 * T_TOK + s1] = t;  wlist[i1 * T_TOK + s1] = w1;
    }
}

__global__ void k_prefix(const int* __restrict__ counts, int* __restrict__ offsets) {
    if (threadIdx.x == 0) {
        int s = 0;
        for (int e = 0; e < EE; e++) { offsets[e] = s; s += counts[e]; }
        offsets[EE] = s;
    }
}

// ---------------- convert x -> bf16 hi (+lo) ----------------
template <bool LO>
__global__ void k_convx(const float* __restrict__ x, u16* __restrict__ xh, u16* __restrict__ xl) {
    size_t i = (size_t)blockIdx.x * 256 + threadIdx.x;
    f32x4 v = ((const f32x4*)x)[i];
    u16x4 h, lo;
#pragma unroll
    for (int j = 0; j < 4; j++) {
        u16 hb = f2bf(v[j]);
        h[j] = hb;
        if (LO) lo[j] = f2bf(v[j] - bf2f(hb));
    }
    ((u16x4*)xh)[i] = h;
    if (LO) ((u16x4*)xl)[i] = lo;
}

// ---------------- transpose+convert: [E][R][C] f32 -> [E][C][R] bf16 hi (+lo) ----------------
template <bool LO>
__global__ void k_transconv(const float* __restrict__ src, u16* __restrict__ dh,
                            u16* __restrict__ dl, int R, int C) {
    __shared__ float tile[32][33];
    int e = blockIdx.z;
    int r0 = blockIdx.x * 32, c0 = blockIdx.y * 32;
    int tx = threadIdx.x & 31, ty = threadIdx.x >> 5;
    const float* s = src + (size_t)e * R * C;
#pragma unroll
    for (int j = 0; j < 4; j++)
        tile[ty + j * 8][tx] = s[(size_t)(r0 + ty + j * 8) * C + (c0 + tx)];
    __syncthreads();
    u16* ph = dh + (size_t)e * R * C;
    u16* pl = dl + (size_t)e * R * C;
#pragma unroll
    for (int j = 0; j < 4; j++) {
        float v = tile[tx][ty + j * 8];
        u16 hb = f2bf(v);
        size_t o = (size_t)(c0 + ty + j * 8) * R + (r0 + tx);
        ph[o] = hb;
        if (LO) pl[o] = f2bf(v - bf2f(hb));
    }
}

// ---------------- GEMM1: h[slot][0..HC) = relu(x[tok] @ w1t[:, ncol0+...]^T + b1) ----------------
// 2-phase dbuf prefetch. Grid: 1-D, XCD-chunked; decomposition nt-fastest (A-tile reuse).
template <int P>
__global__ __launch_bounds__(256, 3) void k_gemm1(
    const u16* __restrict__ xh, const u16* __restrict__ xl,
    const u16* __restrict__ wth, const u16* __restrict__ wtl,
    const float* __restrict__ b1,
    const int* __restrict__ counts, const int* __restrict__ offsets,
    const int* __restrict__ tok,
    u16* __restrict__ hh, u16* __restrict__ hl,
    int HC, int ncol0, int NTB) {
    // bijective XCD chunking (nwg % 8 == 0 by construction: nwg = 8*64*NTB)
    int nwg = gridDim.x;
    int cpx = nwg >> 3;
    int bid = blockIdx.x;
    int swz = (bid & 7) * cpx + (bid >> 3);
    int nt = swz % NTB; int rem = swz / NTB;
    int mt = rem & 63;  int e = rem >> 6;
    int count = counts[e];
    if (mt * 128 >= count) return;
    int hbase = offsets[e];

    __shared__ u16 Ash[2][4096], Bsh[2][4096];
    __shared__ u16 Asl[(P >= 2) ? 2 : 1][(P >= 2) ? 4096 : 64];
    __shared__ u16 Bsl[(P == 3) ? 2 : 1][(P == 3) ? 4096 : 64];

    int tid = threadIdx.x;
    int rA = tid >> 2, kch = tid & 3;
    int slot0 = mt * 128 + rA, slot1 = slot0 + 64;
    int rg0 = (slot0 < count) ? tok[e * T_TOK + slot0] : 0;
    int rg1 = (slot1 < count) ? tok[e * T_TOK + slot1] : 0;
    const u16* a0h = xh + (size_t)rg0 * DD + kch * 8;
    const u16* a1h = xh + (size_t)rg1 * DD + kch * 8;
    const u16* a0l = xl + (size_t)rg0 * DD + kch * 8;
    const u16* a1l = xl + (size_t)rg1 * DD + kch * 8;
    size_t bb0 = ((size_t)e * HH + ncol0 + nt * 128 + rA) * DD + kch * 8;
    size_t bb1 = bb0 + (size_t)64 * DD;
    const u16* pb0h = wth + bb0; const u16* pb1h = wth + bb1;
    const u16* pb0l = wtl + bb0; const u16* pb1l = wtl + bb1;

    int l = tid & 63, w = tid >> 6;
    int wr = w >> 1, wc = w & 1;
    int lm = l & 15, lk = l >> 4;

    f32x4 acc[4][4];
    f32x4 zero = {0.f, 0.f, 0.f, 0.f};
#pragma unroll
    for (int m = 0; m < 4; m++)
#pragma unroll
        for (int n = 0; n < 4; n++) acc[m][n] = zero;

    int aoff[4], boff[4];
#pragma unroll
    for (int m = 0; m < 4; m++) aoff[m] = (wr * 64 + m * 16 + lm) * 32 + lk * 8;
#pragma unroll
    for (int n = 0; n < 4; n++) boff[n] = (wc * 64 + n * 16 + lm) * 32 + lk * 8;

    int o0 = tid * 8, o1 = (tid + 256) * 8;
    auto stage = [&](int cb, int k0) {
        gload16(a0h + k0, &Ash[cb][o0]);
        gload16(a1h + k0, &Ash[cb][o1]);
        gload16(pb0h + k0, &Bsh[cb][o0]);
        gload16(pb1h + k0, &Bsh[cb][o1]);
        if (P >= 2) { gload16(a0l + k0, &Asl[cb][o0]); gload16(a1l + k0, &Asl[cb][o1]); }
        if (P == 3) { gload16(pb0l + k0, &Bsl[cb][o0]); gload16(pb1l + k0, &Bsl[cb][o1]); }
    };

    const int nsteps = DD / 32;
    stage(0, 0);
    __syncthreads();            // tile 0 landed (barrier implies vmcnt(0) drain)
    int cur = 0;
    for (int it = 0; it < nsteps; ++it) {
        if (it + 1 < nsteps) stage(cur ^ 1, (it + 1) * 32);   // issue next tile; flies during compute
        s16x8 ah[4], al[4], bh[4], bl[4];
#pragma unroll
        for (int m = 0; m < 4; m++) {
            ah[m] = *(const s16x8*)(&Ash[cur][aoff[m]]);
            if (P >= 2) al[m] = *(const s16x8*)(&Asl[cur][aoff[m]]);
        }
#pragma unroll
        for (int n = 0; n < 4; n++) {
            bh[n] = *(const s16x8*)(&Bsh[cur][boff[n]]);
            if (P == 3) bl[n] = *(const s16x8*)(&Bsl[cur][boff[n]]);
        }
#pragma unroll
        for (int m = 0; m < 4; m++)
#pragma unroll
            for (int n = 0; n < 4; n++) {
                acc[m][n] = __builtin_amdgcn_mfma_f32_16x16x32_bf16(ah[m], bh[n], acc[m][n], 0, 0, 0);
                if (P >= 2) acc[m][n] = __builtin_amdgcn_mfma_f32_16x16x32_bf16(al[m], bh[n], acc[m][n], 0, 0, 0);
                if (P == 3) acc[m][n] = __builtin_amdgcn_mfma_f32_16x16x32_bf16(ah[m], bl[n], acc[m][n], 0, 0, 0);
            }
        if (it + 1 < nsteps) {
            __syncthreads();    // drains next-tile loads (vmcnt 0) + joins waves; race-free
            cur ^= 1;
        }
    }

#pragma unroll
    for (int n = 0; n < 4; n++) {
        int coln = nt * 128 + wc * 64 + n * 16 + lm;
        float bias = b1[e * HH + ncol0 + coln];
#pragma unroll
        for (int m = 0; m < 4; m++) {
#pragma unroll
            for (int j = 0; j < 4; j++) {
                int slot = mt * 128 + wr * 64 + m * 16 + lk * 4 + j;
                if (slot < count) {
                    float v = fmaxf(acc[m][n][j] + bias, 0.f);
                    u16 hb = f2bf(v);
                    size_t o = (size_t)(hbase + slot) * HC + coln;
                    hh[o] = hb;
                    if (P >= 2) hl[o] = f2bf(v - bf2f(hb));
                }
            }
        }
    }
}

// ---------------- GEMM2: out[tok] += wgt * (h @ w2t[:, ncol0..]^T + biasf*b2) ----------------
template <int P>
__global__ __launch_bounds__(256, 3) void k_gemm2(
    const u16* __restrict__ hh, const u16* __restrict__ hl,
    const u16* __restrict__ wth, const u16* __restrict__ wtl,
    const float* __restrict__ b2,
    const int* __restrict__ counts, const int* __restrict__ offsets,
    const int* __restrict__ tok, const float* __restrict__ wlist,
    float* __restrict__ out, int HC, int ncol0, float biasf) {
    const int NTB = DD / 128;   // 8
    int nwg = gridDim.x;
    int cpx = nwg >> 3;
    int bid = blockIdx.x;
    int swz = (bid & 7) * cpx + (bid >> 3);
    int nt = swz % NTB; int rem = swz / NTB;
    int mt = rem & 63;  int e = rem >> 6;
    int count = counts[e];
    if (mt * 128 >= count) return;
    int hbase = offsets[e];

    __shared__ u16 Ash[2][4096], Bsh[2][4096];
    __shared__ u16 Asl[(P >= 2) ? 2 : 1][(P >= 2) ? 4096 : 64];
    __shared__ u16 Bsl[(P == 3) ? 2 : 1][(P == 3) ? 4096 : 64];

    int tid = threadIdx.x;
    int rA = tid >> 2, kch = tid & 3;
    int slot0 = mt * 128 + rA, slot1 = slot0 + 64;
    int r0 = hbase + min(slot0, count - 1);
    int r1 = hbase + min(slot1, count - 1);
    const u16* a0h = hh + (size_t)r0 * HC + kch * 8;
    const u16* a1h = hh + (size_t)r1 * HC + kch * 8;
    const u16* a0l = hl + (size_t)r0 * HC + kch * 8;
    const u16* a1l = hl + (size_t)r1 * HC + kch * 8;
    size_t bb0 = ((size_t)e * DD + nt * 128 + rA) * HH + ncol0 + kch * 8;
    size_t bb1 = bb0 + (size_t)64 * HH;
    const u16* pb0h = wth + bb0; const u16* pb1h = wth + bb1;
    const u16* pb0l = wtl + bb0; const u16* pb1l = wtl + bb1;

    int l = tid & 63, w = tid >> 6;
    int wr = w >> 1, wc = w & 1;
    int lm = l & 15, lk = l >> 4;

    f32x4 acc[4][4];
    f32x4 zero = {0.f, 0.f, 0.f, 0.f};
#pragma unroll
    for (int m = 0; m < 4; m++)
#pragma unroll
        for (int n = 0; n < 4; n++) acc[m][n] = zero;

    int aoff[4], boff[4];
#pragma unroll
    for (int m = 0; m < 4; m++) aoff[m] = (wr * 64 + m * 16 + lm) * 32 + lk * 8;
#pragma unroll
    for (int n = 0; n < 4; n++) boff[n] = (wc * 64 + n * 16 + lm) * 32 + lk * 8;

    int o0 = tid * 8, o1 = (tid + 256) * 8;
    auto stage = [&](int cb, int k0) {
        gload16(a0h + k0, &Ash[cb][o0]);
        gload16(a1h + k0, &Ash[cb][o1]);
        gload16(pb0h + k0, &Bsh[cb][o0]);
        gload16(pb1h + k0, &Bsh[cb][o1]);
        if (P >= 2) { gload16(a0l + k0, &Asl[cb][o0]); gload16(a1l + k0, &Asl[cb][o1]); }
        if (P == 3) { gload16(pb0l + k0, &Bsl[cb][o0]); gload16(pb1l + k0, &Bsl[cb][o1]); }
    };

    const int nsteps = HC / 32;
    stage(0, 0);
    __syncthreads();
    int cur = 0;
    for (int it = 0; it < nsteps; ++it) {
        if (it + 1 < nsteps) stage(cur ^ 1, (it + 1) * 32);
        s16x8 ah[4], al[4], bh[4], bl[4];
#pragma unroll
        for (int m = 0; m < 4; m++) {
            ah[m] = *(const s16x8*)(&Ash[cur][aoff[m]]);
            if (P >= 2) al[m] = *(const s16x8*)(&Asl[cur][aoff[m]]);
        }
#pragma unroll
        for (int n = 0; n < 4; n++) {
            bh[n] = *(const s16x8*)(&Bsh[cur][boff[n]]);
            if (P == 3) bl[n] = *(const s16x8*)(&Bsl[cur][boff[n]]);
        }
#pragma unroll
        for (int m = 0; m < 4; m++)
#pragma unroll
            for (int n = 0; n < 4; n++) {
                acc[m][n] = __builtin_amdgcn_mfma_f32_16x16x32_bf16(ah[m], bh[n], acc[m][n], 0, 0, 0);
                if (P >= 2) acc[m][n] = __builtin_amdgcn_mfma_f32_16x16x32_bf16(al[m], bh[n], acc[m][n], 0, 0, 0);
                if (P == 3) acc[m][n] = __builtin_amdgcn_mfma_f32_16x16x32_bf16(ah[m], bl[n], acc[m][n], 0, 0, 0);
            }
        if (it + 1 < nsteps) {
            __syncthreads();
            cur ^= 1;
        }
    }

#pragma unroll
    for (int m = 0; m < 4; m++) {
        int tk[4]; float wt[4];
#pragma unroll
        for (int j = 0; j < 4; j++) {
            int slot = mt * 128 + wr * 64 + m * 16 + lk * 4 + j;
            if (slot < count) { tk[j] = tok[e * T_TOK + slot]; wt[j] = wlist[e * T_TOK + slot]; }
            else { tk[j] = -1; wt[j] = 0.f; }
        }
#pragma unroll
        for (int n = 0; n < 4; n++) {
            int coln = nt * 128 + wc * 64 + n * 16 + lm;
            float bias = biasf * b2[e * DD + coln];
#pragma unroll
            for (int j = 0; j < 4; j++) {
                if (tk[j] >= 0)
                    atomicAdd(out + (size_t)tk[j] * DD + coln, wt[j] * (acc[m][n][j] + bias));
            }
        }
    }
}

extern "C" void kernel_launch(void* const* d_in, const int* in_sizes, int n_in,
                              void* d_out, int out_size, void* d_ws, size_t ws_size,
                              hipStream_t stream) {
    const float* x  = (const float*)d_in[0];
    const float* gw = (const float*)d_in[1];
    const float* w1 = (const float*)d_in[2];
    const float* b1 = (const float*)d_in[3];
    const float* w2 = (const float*)d_in[4];
    const float* b2 = (const float*)d_in[5];
    float* out = (float*)d_out;

    // ---- tier & chunk selection from ws_size (deterministic; graph-capture-safe) ----
    auto need = [](int P, int hc) -> size_t {
        size_t s = 1 << 20;
        s += (size_t)T_TOK * DD * 2 * (P >= 2 ? 2 : 1);
        s += (size_t)EE * HH * DD * 2 * 2 * (P == 3 ? 2 : 1);
        s += (size_t)2 * T_TOK * hc * 2 * (P >= 2 ? 2 : 1);
        return s;
    };
    // Default to P=2 (weights single-bf16): 2/3 MFMA work, 48KB LDS -> 3 blocks/CU.
    int P = (need(2, 128) <= ws_size) ? 2 : 1;
    int HC = 128;
    const int hcs[6] = {4096, 2048, 1024, 512, 256, 128};
    for (int i = 0; i < 6; i++) if (need(P, hcs[i]) <= ws_size) { HC = hcs[i]; break; }

    // ---- workspace layout ----
    char* ws = (char*)d_ws;
    size_t p = 0;
    auto take = [&](size_t bytes) { size_t o = p; p = (p + bytes + 255) & ~(size_t)255; return o; };
    int*   counts  = (int*)(ws + take(64));
    int*   offsets = (int*)(ws + take(64));
    int*   tok     = (int*)(ws + take((size_t)EE * T_TOK * 4));
    float* wlist   = (float*)(ws + take((size_t)EE * T_TOK * 4));
    u16*   xhp     = (u16*)(ws + take((size_t)T_TOK * DD * 2));
    u16*   xlp     = (P >= 2) ? (u16*)(ws + take((size_t)T_TOK * DD * 2)) : nullptr;
    u16*   w1th    = (u16*)(ws + take((size_t)EE * HH * DD * 2));
    u16*   w2th    = (u16*)(ws + take((size_t)EE * HH * DD * 2));
    u16*   w1tl    = (P == 3) ? (u16*)(ws + take((size_t)EE * HH * DD * 2)) : nullptr;
    u16*   w2tl    = (P == 3) ? (u16*)(ws + take((size_t)EE * HH * DD * 2)) : nullptr;
    u16*   hhp     = (u16*)(ws + take((size_t)2 * T_TOK * HC * 2));
    u16*   hlp     = (P >= 2) ? (u16*)(ws + take((size_t)2 * T_TOK * HC * 2)) : nullptr;

    // ---- pipeline ----
    k_zero<<<8192, 256, 0, stream>>>(out, counts);
    k_gating<<<2048, 256, 0, stream>>>(x, gw, out + (size_t)T_TOK * DD, counts, tok, wlist);
    k_prefix<<<1, 64, 0, stream>>>(counts, offsets);
    if (P >= 2) k_convx<true><<<8192, 256, 0, stream>>>(x, xhp, xlp);
    else        k_convx<false><<<8192, 256, 0, stream>>>(x, xhp, nullptr);
    if (P == 3) {
        k_transconv<true><<<dim3(32, 128, 8), 256, 0, stream>>>(w1, w1th, w1tl, DD, HH);
        k_transconv<true><<<dim3(128, 32, 8), 256, 0, stream>>>(w2, w2th, w2tl, HH, DD);
    } else {
        k_transconv<false><<<dim3(32, 128, 8), 256, 0, stream>>>(w1, w1th, nullptr, DD, HH);
        k_transconv<false><<<dim3(128, 32, 8), 256, 0, stream>>>(w2, w2th, nullptr, HH, DD);
    }
    int nchunk = HH / HC;
    int NTB1 = HC / 128;
    dim3 g1(EE * 64 * NTB1), g2(EE * 64 * (DD / 128));
    for (int c = 0; c < nchunk; c++) {
        int ncol0 = c * HC;
        float biasf = (c == 0) ? 1.f : 0.f;
        if (P == 3) {
            k_gemm1<3><<<g1, 256, 0, stream>>>(xhp, xlp, w1th, w1tl, b1, counts, offsets, tok, hhp, hlp, HC, ncol0, NTB1);
            k_gemm2<3><<<g2, 256, 0, stream>>>(hhp, hlp, w2th, w2tl, b2, counts, offsets, tok, wlist, out, HC, ncol0, biasf);
        } else if (P == 2) {
            k_gemm1<2><<<g1, 256, 0, stream>>>(xhp, xlp, w1th, nullptr, b1, counts, offsets, tok, hhp, hlp, HC, ncol0, NTB1);
            k_gemm2<2><<<g2, 256, 0, stream>>>(hhp, hlp, w2th, nullptr, b2, counts, offsets, tok, wlist, out, HC, ncol0, biasf);
        } else {
            k_gemm1<1><<<g1, 256, 0, stream>>>(xhp, nullptr, w1th, nullptr, b1, counts, offsets, tok, hhp, nullptr, HC, ncol0, NTB1);
            k_gemm2<1><<<g2, 256, 0, stream>>>(hhp, nullptr, w2th, nullptr, b2, counts, offsets, tok, wlist, out, HC, ncol0, biasf);
        }
    }
}

// Round 13
// 1053.257 us; speedup vs baseline: 2.2663x; 1.3304x over previous
//
#include <hip/hip_runtime.h>

// MoE fused: B=4,S=2048,D=1024,E=8,H=4096,TOPK=2, fp32 in/out.
// R10-R13: P=1 (plain bf16 MFMA both GEMMs; absmax evidence shows ref-error dominates) ->
//   half the MFMA work of R9, 4 stage-loads/K-step, LDS 32KB dbuf. k_zero fused into k_convx.
// zero+convx -> gating(fp64 acc, top2, softmax) -> prefix -> transpose+convert w1,w2
// -> gemm1 (x@w1+b1, relu) -> gemm2 (h@w2+b2, *wgt, atomicAdd out)   [single chunk HC=4096]

typedef unsigned short u16;
typedef unsigned int u32;
typedef float f32x4 __attribute__((ext_vector_type(4)));
typedef short s16x8 __attribute__((ext_vector_type(8)));
typedef u16 u16x4 __attribute__((ext_vector_type(4)));

#define T_TOK 8192
#define DD 1024
#define EE 8
#define HH 4096

__device__ __forceinline__ u16 f2bf(float f) {
    u32 u = __builtin_bit_cast(u32, f);
    u32 r = u + 0x7FFFu + ((u >> 16) & 1u);   // RNE
    return (u16)(r >> 16);
}
__device__ __forceinline__ float bf2f(u16 h) {
    return __builtin_bit_cast(float, (u32)h << 16);
}
__device__ __forceinline__ void gload16(const u16* g, u16* l) {
    __builtin_amdgcn_global_load_lds((const __attribute__((address_space(1))) void*)g,
                                     (__attribute__((address_space(3))) void*)l, 16, 0, 0);
}

// ---------------- fused: zero out + zero counts + convert x -> bf16 ----------------
__global__ void k_zero_convx(const float* __restrict__ x, float* __restrict__ out,
                             int* __restrict__ counts, u16* __restrict__ xh) {
    size_t i = (size_t)blockIdx.x * 256 + threadIdx.x;   // 8192 blocks: T*D/4 float4
    f32x4 z = {0.f, 0.f, 0.f, 0.f};
    ((f32x4*)out)[i] = z;
    f32x4 v = ((const f32x4*)x)[i];
    u16x4 h;
#pragma unroll
    for (int j = 0; j < 4; j++) h[j] = f2bf(v[j]);
    ((u16x4*)xh)[i] = h;
    if (i < EE) counts[i] = 0;
}

// ---------------- gating: fp64-accum logits, top2, softmax over the pair ----------------
__global__ void k_gating(const float* __restrict__ x, const float* __restrict__ gw,
                         float* __restrict__ sel_out, int* __restrict__ counts,
                         int* __restrict__ tok, float* __restrict__ wlist) {
    int t = blockIdx.x * 4 + (threadIdx.x >> 6);
    int l = threadIdx.x & 63;
    const float* xr = x + (size_t)t * DD;
    double acc[EE];
#pragma unroll
    for (int e = 0; e < EE; e++) acc[e] = 0.0;
    for (int d = l; d < DD; d += 64) {
        double xv = (double)xr[d];
        const float* g = gw + (size_t)d * EE;
#pragma unroll
        for (int e = 0; e < EE; e++) acc[e] = fma(xv, (double)g[e], acc[e]);
    }
#pragma unroll
    for (int off = 32; off > 0; off >>= 1) {
#pragma unroll
        for (int e = 0; e < EE; e++) acc[e] += __shfl_down(acc[e], off, 64);
    }
    if (l == 0) {
        float af[EE];
#pragma unroll
        for (int e = 0; e < EE; e++) af[e] = (float)acc[e];
        int i0 = 0; float v0 = af[0];
#pragma unroll
        for (int e = 1; e < EE; e++) if (af[e] > v0) { v0 = af[e]; i0 = e; }
        int i1 = -1; float v1 = -3.4e38f;
#pragma unroll
        for (int e = 0; e < EE; e++) if (e != i0 && af[e] > v1) { v1 = af[e]; i1 = e; }
        float ex = expf(v1 - v0);
        float den = 1.f + ex;
        float w0 = 1.f / den, w1 = ex / den;
        sel_out[(size_t)t * 2]     = (float)i0;
        sel_out[(size_t)t * 2 + 1] = (float)i1;
        int s0 = atomicAdd(&counts[i0], 1);
        tok[i0 * T_TOK + s0] = t;  wlist[i0 * T_TOK + s0] = w0;
        int s1 = atomicAdd(&counts[i1], 1);
        tok[i1 * T_TOK + s1] = t;  wlist[i1 * T_TOK + s1] = w1;
    }
}

__global__ void k_prefix(const int* __restrict__ counts, int* __restrict__ offsets) {
    if (threadIdx.x == 0) {
        int s = 0;
        for (int e = 0; e < EE; e++) { offsets[e] = s; s += counts[e]; }
        offsets[EE] = s;
    }
}

// ---------------- transpose+convert: [E][R][C] f32 -> [E][C][R] bf16 ----------------
__global__ void k_transconv(const float* __restrict__ src, u16* __restrict__ dh, int R, int C) {
    __shared__ float tile[32][33];
    int e = blockIdx.z;
    int r0 = blockIdx.x * 32, c0 = blockIdx.y * 32;
    int tx = threadIdx.x & 31, ty = threadIdx.x >> 5;
    const float* s = src + (size_t)e * R * C;
#pragma unroll
    for (int j = 0; j < 4; j++)
        tile[ty + j * 8][tx] = s[(size_t)(r0 + ty + j * 8) * C + (c0 + tx)];
    __syncthreads();
    u16* ph = dh + (size_t)e * R * C;
#pragma unroll
    for (int j = 0; j < 4; j++) {
        float v = tile[tx][ty + j * 8];
        size_t o = (size_t)(c0 + ty + j * 8) * R + (r0 + tx);
        ph[o] = f2bf(v);
    }
}

// ---------------- GEMM1: h[slot][0..HC) = relu(x[tok] @ w1t[:, ncol0+...]^T + b1) ----------------
// plain-bf16 (P=1). 2-phase dbuf prefetch; 1-D grid, XCD-chunked, nt-fastest decomposition.
__global__ __launch_bounds__(256, 4) void k_gemm1(
    const u16* __restrict__ xh,
    const u16* __restrict__ wth,
    const float* __restrict__ b1,
    const int* __restrict__ counts, const int* __restrict__ offsets,
    const int* __restrict__ tok,
    u16* __restrict__ hh,
    int HC, int ncol0, int NTB) {
    int nwg = gridDim.x;
    int cpx = nwg >> 3;
    int bid = blockIdx.x;
    int swz = (bid & 7) * cpx + (bid >> 3);
    int nt = swz % NTB; int rem = swz / NTB;
    int mt = rem & 63;  int e = rem >> 6;
    int count = counts[e];
    if (mt * 128 >= count) return;
    int hbase = offsets[e];

    __shared__ u16 Ash[2][4096], Bsh[2][4096];

    int tid = threadIdx.x;
    int rA = tid >> 2, kch = tid & 3;
    int slot0 = mt * 128 + rA, slot1 = slot0 + 64;
    int rg0 = (slot0 < count) ? tok[e * T_TOK + slot0] : 0;
    int rg1 = (slot1 < count) ? tok[e * T_TOK + slot1] : 0;
    const u16* a0h = xh + (size_t)rg0 * DD + kch * 8;
    const u16* a1h = xh + (size_t)rg1 * DD + kch * 8;
    size_t bb0 = ((size_t)e * HH + ncol0 + nt * 128 + rA) * DD + kch * 8;
    size_t bb1 = bb0 + (size_t)64 * DD;
    const u16* pb0h = wth + bb0; const u16* pb1h = wth + bb1;

    int l = tid & 63, w = tid >> 6;
    int wr = w >> 1, wc = w & 1;
    int lm = l & 15, lk = l >> 4;

    f32x4 acc[4][4];
    f32x4 zero = {0.f, 0.f, 0.f, 0.f};
#pragma unroll
    for (int m = 0; m < 4; m++)
#pragma unroll
        for (int n = 0; n < 4; n++) acc[m][n] = zero;

    int aoff[4], boff[4];
#pragma unroll
    for (int m = 0; m < 4; m++) aoff[m] = (wr * 64 + m * 16 + lm) * 32 + lk * 8;
#pragma unroll
    for (int n = 0; n < 4; n++) boff[n] = (wc * 64 + n * 16 + lm) * 32 + lk * 8;

    int o0 = tid * 8, o1 = (tid + 256) * 8;
    auto stage = [&](int cb, int k0) {
        gload16(a0h + k0, &Ash[cb][o0]);
        gload16(a1h + k0, &Ash[cb][o1]);
        gload16(pb0h + k0, &Bsh[cb][o0]);
        gload16(pb1h + k0, &Bsh[cb][o1]);
    };

    const int nsteps = DD / 32;
    stage(0, 0);
    __syncthreads();            // tile 0 landed (barrier implies vmcnt(0) drain)
    int cur = 0;
    for (int it = 0; it < nsteps; ++it) {
        if (it + 1 < nsteps) stage(cur ^ 1, (it + 1) * 32);
        s16x8 ah[4], bh[4];
#pragma unroll
        for (int m = 0; m < 4; m++) ah[m] = *(const s16x8*)(&Ash[cur][aoff[m]]);
#pragma unroll
        for (int n = 0; n < 4; n++) bh[n] = *(const s16x8*)(&Bsh[cur][boff[n]]);
#pragma unroll
        for (int m = 0; m < 4; m++)
#pragma unroll
            for (int n = 0; n < 4; n++)
                acc[m][n] = __builtin_amdgcn_mfma_f32_16x16x32_bf16(ah[m], bh[n], acc[m][n], 0, 0, 0);
        if (it + 1 < nsteps) {
            __syncthreads();
            cur ^= 1;
        }
    }

#pragma unroll
    for (int n = 0; n < 4; n++) {
        int coln = nt * 128 + wc * 64 + n * 16 + lm;
        float bias = b1[e * HH + ncol0 + coln];
#pragma unroll
        for (int m = 0; m < 4; m++) {
#pragma unroll
            for (int j = 0; j < 4; j++) {
                int slot = mt * 128 + wr * 64 + m * 16 + lk * 4 + j;
                if (slot < count) {
                    float v = fmaxf(acc[m][n][j] + bias, 0.f);
                    hh[(size_t)(hbase + slot) * HC + coln] = f2bf(v);
                }
            }
        }
    }
}

// ---------------- GEMM2: out[tok] += wgt * (h @ w2t[:, ncol0..]^T + biasf*b2) ----------------
__global__ __launch_bounds__(256, 4) void k_gemm2(
    const u16* __restrict__ hh,
    const u16* __restrict__ wth,
    const float* __restrict__ b2,
    const int* __restrict__ counts, const int* __restrict__ offsets,
    const int* __restrict__ tok, const float* __restrict__ wlist,
    float* __restrict__ out, int HC, int ncol0, float biasf) {
    const int NTB = DD / 128;   // 8
    int nwg = gridDim.x;
    int cpx = nwg >> 3;
    int bid = blockIdx.x;
    int swz = (bid & 7) * cpx + (bid >> 3);
    int nt = swz % NTB; int rem = swz / NTB;
    int mt = rem & 63;  int e = rem >> 6;
    int count = counts[e];
    if (mt * 128 >= count) return;
    int hbase = offsets[e];

    __shared__ u16 Ash[2][4096], Bsh[2][4096];

    int tid = threadIdx.x;
    int rA = tid >> 2, kch = tid & 3;
    int slot0 = mt * 128 + rA, slot1 = slot0 + 64;
    int r0 = hbase + min(slot0, count - 1);
    int r1 = hbase + min(slot1, count - 1);
    const u16* a0h = hh + (size_t)r0 * HC + kch * 8;
    const u16* a1h = hh + (size_t)r1 * HC + kch * 8;
    size_t bb0 = ((size_t)e * DD + nt * 128 + rA) * HH + ncol0 + kch * 8;
    size_t bb1 = bb0 + (size_t)64 * HH;
    const u16* pb0h = wth + bb0; const u16* pb1h = wth + bb1;

    int l = tid & 63, w = tid >> 6;
    int wr = w >> 1, wc = w & 1;
    int lm = l & 15, lk = l >> 4;

    f32x4 acc[4][4];
    f32x4 zero = {0.f, 0.f, 0.f, 0.f};
#pragma unroll
    for (int m = 0; m < 4; m++)
#pragma unroll
        for (int n = 0; n < 4; n++) acc[m][n] = zero;

    int aoff[4], boff[4];
#pragma unroll
    for (int m = 0; m < 4; m++) aoff[m] = (wr * 64 + m * 16 + lm) * 32 + lk * 8;
#pragma unroll
    for (int n = 0; n < 4; n++) boff[n] = (wc * 64 + n * 16 + lm) * 32 + lk * 8;

    int o0 = tid * 8, o1 = (tid + 256) * 8;
    auto stage = [&](int cb, int k0) {
        gload16(a0h + k0, &Ash[cb][o0]);
        gload16(a1h + k0, &Ash[cb][o1]);
        gload16(pb0h + k0, &Bsh[cb][o0]);
        gload16(pb1h + k0, &Bsh[cb][o1]);
    };

    const int nsteps = HC / 32;
    stage(0, 0);
    __syncthreads();
    int cur = 0;
    for (int it = 0; it < nsteps; ++it) {
        if (it + 1 < nsteps) stage(cur ^ 1, (it + 1) * 32);
        s16x8 ah[4], bh[4];
#pragma unroll
        for (int m = 0; m < 4; m++) ah[m] = *(const s16x8*)(&Ash[cur][aoff[m]]);
#pragma unroll
        for (int n = 0; n < 4; n++) bh[n] = *(const s16x8*)(&Bsh[cur][boff[n]]);
#pragma unroll
        for (int m = 0; m < 4; m++)
#pragma unroll
            for (int n = 0; n < 4; n++)
                acc[m][n] = __builtin_amdgcn_mfma_f32_16x16x32_bf16(ah[m], bh[n], acc[m][n], 0, 0, 0);
        if (it + 1 < nsteps) {
            __syncthreads();
            cur ^= 1;
        }
    }

#pragma unroll
    for (int m = 0; m < 4; m++) {
        int tk[4]; float wt[4];
#pragma unroll
        for (int j = 0; j < 4; j++) {
            int slot = mt * 128 + wr * 64 + m * 16 + lk * 4 + j;
            if (slot < count) { tk[j] = tok[e * T_TOK + slot]; wt[j] = wlist[e * T_TOK + slot]; }
            else { tk[j] = -1; wt[j] = 0.f; }
        }
#pragma unroll
        for (int n = 0; n < 4; n++) {
            int coln = nt * 128 + wc * 64 + n * 16 + lm;
            float bias = biasf * b2[e * DD + coln];
#pragma unroll
            for (int j = 0; j < 4; j++) {
                if (tk[j] >= 0)
                    atomicAdd(out + (size_t)tk[j] * DD + coln, wt[j] * (acc[m][n][j] + bias));
            }
        }
    }
}

extern "C" void kernel_launch(void* const* d_in, const int* in_sizes, int n_in,
                              void* d_out, int out_size, void* d_ws, size_t ws_size,
                              hipStream_t stream) {
    const float* x  = (const float*)d_in[0];
    const float* gw = (const float*)d_in[1];
    const float* w1 = (const float*)d_in[2];
    const float* b1 = (const float*)d_in[3];
    const float* w2 = (const float*)d_in[4];
    const float* b2 = (const float*)d_in[5];
    float* out = (float*)d_out;

    // ---- chunk selection (P=1 fixed) ----
    auto need = [](int hc) -> size_t {
        size_t s = 1 << 20;
        s += (size_t)T_TOK * DD * 2;                 // x bf16
        s += (size_t)EE * HH * DD * 2 * 2;           // w1t + w2t bf16
        s += (size_t)2 * T_TOK * hc * 2;             // h chunk bf16
        return s;
    };
    int HC = 128;
    const int hcs[6] = {4096, 2048, 1024, 512, 256, 128};
    for (int i = 0; i < 6; i++) if (need(hcs[i]) <= ws_size) { HC = hcs[i]; break; }

    // ---- workspace layout ----
    char* ws = (char*)d_ws;
    size_t p = 0;
    auto take = [&](size_t bytes) { size_t o = p; p = (p + bytes + 255) & ~(size_t)255; return o; };
    int*   counts  = (int*)(ws + take(64));
    int*   offsets = (int*)(ws + take(64));
    int*   tok     = (int*)(ws + take((size_t)EE * T_TOK * 4));
    float* wlist   = (float*)(ws + take((size_t)EE * T_TOK * 4));
    u16*   xhp     = (u16*)(ws + take((size_t)T_TOK * DD * 2));
    u16*   w1th    = (u16*)(ws + take((size_t)EE * HH * DD * 2));
    u16*   w2th    = (u16*)(ws + take((size_t)EE * HH * DD * 2));
    u16*   hhp     = (u16*)(ws + take((size_t)2 * T_TOK * HC * 2));

    // ---- pipeline ----
    k_zero_convx<<<8192, 256, 0, stream>>>(x, out, counts, xhp);
    k_gating<<<2048, 256, 0, stream>>>(x, gw, out + (size_t)T_TOK * DD, counts, tok, wlist);
    k_prefix<<<1, 64, 0, stream>>>(counts, offsets);
    k_transconv<<<dim3(32, 128, 8), 256, 0, stream>>>(w1, w1th, DD, HH);
    k_transconv<<<dim3(128, 32, 8), 256, 0, stream>>>(w2, w2th, HH, DD);
    int nchunk = HH / HC;
    int NTB1 = HC / 128;
    dim3 g1(EE * 64 * NTB1), g2(EE * 64 * (DD / 128));
    for (int c = 0; c < nchunk; c++) {
        int ncol0 = c * HC;
        float biasf = (c == 0) ? 1.f : 0.f;
        k_gemm1<<<g1, 256, 0, stream>>>(xhp, w1th, b1, counts, offsets, tok, hhp, HC, ncol0, NTB1);
        k_gemm2<<<g2, 256, 0, stream>>>(hhp, w2th, b2, counts, offsets, tok, wlist, out, HC, ncol0, biasf);
    }
}